// Round 19
// baseline (60.432 us; speedup 1.0000x reference)
//
#include <hip/hip_runtime.h>

#define BATCH 4
#define NPTS 8192
#define DIM 128
#define TOTAL_ROWS (BATCH * NPTS)   // 32768
#define SLICES 8                    // m-slices per batch
#define SLICE_W 1024                // cols per slice
#define ITERS 64                    // 16-col tiles per slice
#define TILES_PER_B 512             // NPTS/16
#define TILE_B 2048                 // bytes per packed fp8 16-col tile

typedef __attribute__((ext_vector_type(8))) int   i32x8;
typedef __attribute__((ext_vector_type(4))) float f32x4;

// monotonic encoding of float for unsigned atomicMin (3 ops: ashr, or, xor)
__device__ __forceinline__ unsigned encf(float f) {
  unsigned b = __float_as_uint(f);
  return b ^ ((unsigned)((int)b >> 31) | 0x80000000u);
}
__device__ __forceinline__ float decf(unsigned u) {
  unsigned b = (u & 0x80000000u) ? (u ^ 0x80000000u) : ~u;
  return __uint_as_float(b);
}

// pack 8 floats -> 8 fp8(e4m3) bytes in 2 dwords
__device__ __forceinline__ void pk8(const float4& x, const float4& y,
                                    unsigned& lo, unsigned& hi) {
  lo = __builtin_amdgcn_cvt_pk_fp8_f32(x.x, x.y, 0, 0);
  lo = __builtin_amdgcn_cvt_pk_fp8_f32(x.z, x.w, lo, 1);
  hi = __builtin_amdgcn_cvt_pk_fp8_f32(y.x, y.y, 0, 0);
  hi = __builtin_amdgcn_cvt_pk_fp8_f32(y.z, y.w, hi, 1);
}

// ---- fused pack: blocks <2048 pack f_ (pkB,gnh); >=2048 pack f (pkA,fnh).
// Each block also inits 8 entries of rowmin + colmin (replaces 2 memsets).
// Layout: lane fl's 32 k-bytes CONTIGUOUS at tile_base + fl*32.
__global__ void pack_kernel(const float* __restrict__ f,
                            const float* __restrict__ f_,
                            unsigned char* __restrict__ pkA,
                            unsigned char* __restrict__ pkB,
                            float* __restrict__ fnh,
                            float* __restrict__ gnh,
                            unsigned int* __restrict__ rowmin,
                            unsigned int* __restrict__ colmin) {
  __shared__ float sred[16][17];
  int gb  = blockIdx.x;                // 0..4095
  int tl  = threadIdx.x;               // 0..255
  // init min buffers: 8 entries each per block
  if (tl < 8)        rowmin[gb * 8 + tl]       = 0xFFFFFFFFu;
  else if (tl < 16)  colmin[gb * 8 + (tl - 8)] = 0xFFFFFFFFu;

  const int isA = gb >> 11;            // 0: f_ -> pkB ; 1: f -> pkA
  const float* in = isA ? f : f_;
  unsigned char* pk = isA ? pkA : pkB;
  float* n2h = isA ? fnh : gnh;

  int fl  = tl >> 2;                   // fragment lane 0..63
  int p   = tl & 3;                    // 8-byte group within lane's 32
  int row = fl & 15, kch = fl >> 4;
  int tile = gb & 2047;                // b*512 + mtg
  int b = tile >> 9, mtg = tile & 511;
  const float* src = in + (size_t)(b * NPTS + mtg * 16 + row) * DIM + kch * 32 + p * 8;
  float4 x = ((const float4*)src)[0], y = ((const float4*)src)[1];
  unsigned lo, hi;
  pk8(x, y, lo, hi);
  *(uint2*)(pk + (size_t)tile * TILE_B + fl * 32 + p * 8) = make_uint2(lo, hi);
  float s = 0.f;
  s = fmaf(x.x, x.x, s); s = fmaf(x.y, x.y, s);
  s = fmaf(x.z, x.z, s); s = fmaf(x.w, x.w, s);
  s = fmaf(y.x, y.x, s); s = fmaf(y.y, y.y, s);
  s = fmaf(y.z, y.z, s); s = fmaf(y.w, y.w, s);
  sred[row][kch * 4 + p] = s;
  __syncthreads();
  if (tl < 16) {
    float t = 0.f;
    #pragma unroll
    for (int j = 0; j < 16; ++j) t += sred[tl][j];
    n2h[tile * 16 + tl] = -0.5f * t;   // store -n2/2 (saves per-iter mul)
  }
}

// ---- main: per wave, 64 f-rows (packed fp8 A) x 1024-col slice ----
// (byte-identical to R18's main kernel)
__global__ __launch_bounds__(256, 4)
void chamfer_mfma_kernel(const unsigned char* __restrict__ pkA,
                         const unsigned char* __restrict__ pkB,
                         const float* __restrict__ fnh,
                         const float* __restrict__ gnh,
                         unsigned int* __restrict__ rowmin,
                         unsigned int* __restrict__ colmin) {
  const int lane = threadIdx.x & 63;
  const int l15  = lane & 15;
  const int q    = lane >> 4;                       // 0..3
  const int widx = threadIdx.x >> 6;                // 0..3
  const int loff = lane * 32;                       // per-lane byte offset

  // XCD-aware: 4 (b,slice) combos per XCD, 32 row-groups each
  const int bid   = blockIdx.x;                     // 0..1023
  const int combo = (bid & 7) * 4 + ((bid >> 3) & 3);  // 0..31
  const int b     = combo >> 3;
  const int slice = combo & 7;
  const int rgrp  = bid >> 5;                       // 0..31
  const int r0    = rgrp * 256 + widx * 64;
  const int bN    = b * NPTS;
  const int tile0 = b * TILES_PER_B + slice * ITERS;

  // block-level column-max accumulator of encf(-2*cmax); gn added at merge
  __shared__ unsigned cl[SLICE_W];
  #pragma unroll
  for (int k = 0; k < SLICE_W / 256; ++k)
    cl[threadIdx.x + k * 256] = 0xFFFFFFFFu;
  __syncthreads();

  // ---- A fragments from packed pkA (uniform base + loff) ----
  i32x8 af[4];
  const int atile0 = b * TILES_PER_B + (r0 >> 4);
  #pragma unroll
  for (int t = 0; t < 4; ++t) {
    const unsigned char* ub = pkA + (size_t)(atile0 + t) * TILE_B;
    af[t] = *(const i32x8*)(ub + loff);
  }
  // C-seeds h = -fn2/2 (pre-halved in fnh) for this lane's C rows
  f32x4 h[4];
  #pragma unroll
  for (int t = 0; t < 4; ++t)
    #pragma unroll
    for (int i = 0; i < 4; ++i)
      h[t][i] = fnh[bN + r0 + t * 16 + q * 4 + i];

  float rowmax[4][4];
  #pragma unroll
  for (int t = 0; t < 4; ++t)
    #pragma unroll
    for (int i = 0; i < 4; ++i) rowmax[t][i] = -3.4e38f;

  const unsigned char* pkw = pkB + (size_t)tile0 * TILE_B;  // uniform
  const float*         gnb = gnh + bN + slice * SLICE_W;

  auto loadB = [&](int mt, i32x8& bf, float& gv) {
    const unsigned char* ub = pkw + (size_t)mt * TILE_B;    // uniform + SALU
    bf = *(const i32x8*)(ub + loff);
    gv = gnb[mt * 16 + l15];                                // = -gn2/2
  };

  auto compute = [&](const i32x8& bf, float g2, int mt) {
    // acc = dot - fn2[r]/2 (C-operand seeded)
    f32x4 acc[4];
    __builtin_amdgcn_s_setprio(1);
    #pragma unroll
    for (int t = 0; t < 4; ++t)
      acc[t] = __builtin_amdgcn_mfma_scale_f32_16x16x128_f8f6f4(
          af[t], bf, h[t], 0, 0, 0, 0x7f7f7f7f, 0, 0x7f7f7f7f);
    __builtin_amdgcn_s_setprio(0);

    // row side: rowmax tracks max(acc + g2) = -dis/2  (g2 = -gn2/2, per lane)
    #pragma unroll
    for (int t = 0; t < 4; ++t)
      #pragma unroll
      for (int i = 0; i < 4; ++i)
        rowmax[t][i] = fmaxf(rowmax[t][i], acc[t][i] + g2);

    // col side: cmax over the 16 raw acc (max3-fused tree)
    float m0 = fmaxf(fmaxf(acc[0][0], acc[0][1]), acc[0][2]);
    float m1 = fmaxf(fmaxf(acc[0][3], acc[1][0]), acc[1][1]);
    float m2 = fmaxf(fmaxf(acc[1][2], acc[1][3]), acc[2][0]);
    float m3 = fmaxf(fmaxf(acc[2][1], acc[2][2]), acc[2][3]);
    float m4 = fmaxf(fmaxf(acc[3][0], acc[3][1]), acc[3][2]);
    float n0 = fmaxf(fmaxf(m0, m1), m2);
    float n1 = fmaxf(fmaxf(m3, m4), acc[3][3]);
    float cmax = fmaxf(n0, n1);
    // fire-and-forget LDS atomic (4-way same-address per col)
    atomicMin(&cl[mt * 16 + l15], encf(-2.f * cmax));
  };

  // 2-deep ping-pong
  i32x8 bA, bB;
  float gA, gB;
  loadB(0, bA, gA);
  for (int mt = 0; mt < ITERS; mt += 2) {
    loadB(mt + 1, bB, gB);
    compute(bA, gA, mt);
    loadB((mt + 2) & (ITERS - 1), bA, gA);
    compute(bB, gB, mt + 1);
  }

  // finalize row mins: reduce MAX over the 16 column-lanes, dis = -2*max
  #pragma unroll
  for (int t = 0; t < 4; ++t)
    #pragma unroll
    for (int i = 0; i < 4; ++i) {
      float v = rowmax[t][i];
      v = fmaxf(v, __shfl_xor(v, 1));
      v = fmaxf(v, __shfl_xor(v, 2));
      v = fmaxf(v, __shfl_xor(v, 4));
      v = fmaxf(v, __shfl_xor(v, 8));
      if (l15 == 0)
        atomicMin(&rowmin[bN + r0 + t * 16 + q * 4 + i], encf(-2.f * v));
    }

  // merge block col maxes: dis = decoded(-2*cmax) + gn2 = decoded - 2*gnh
  __syncthreads();
  #pragma unroll
  for (int k = 0; k < SLICE_W / 256; ++k) {
    int c = threadIdx.x + k * 256;
    float d = decf(cl[c]) - 2.f * gnb[c];
    atomicMin(&colmin[bN + slice * SLICE_W + c], encf(d));
  }
}

// ---- single-kernel reduction: 1 block x 1024 thr, grid-stride ----
__global__ void reduce_kernel(const unsigned int* __restrict__ rowmin,
                              const unsigned int* __restrict__ colmin,
                              float* __restrict__ out) {
  __shared__ float sbuf[16];
  float s = 0.f;
  for (int i = threadIdx.x; i < TOTAL_ROWS; i += 1024)
    s += decf(rowmin[i]) + decf(colmin[i]);
  #pragma unroll
  for (int o = 32; o >= 1; o >>= 1) s += __shfl_xor(s, o);
  if ((threadIdx.x & 63) == 0) sbuf[threadIdx.x >> 6] = s;
  __syncthreads();
  if (threadIdx.x == 0) {
    float t = 0.f;
    #pragma unroll
    for (int j = 0; j < 16; ++j) t += sbuf[j];
    out[0] = t / (float)TOTAL_ROWS;
  }
}

extern "C" void kernel_launch(void* const* d_in, const int* in_sizes, int n_in,
                              void* d_out, int out_size, void* d_ws, size_t ws_size,
                              hipStream_t stream) {
  (void)in_sizes; (void)n_in; (void)out_size; (void)ws_size;
  const float* f  = (const float*)d_in[0];
  const float* f_ = (const float*)d_in[1];

  char* ws = (char*)d_ws;
  unsigned char* pkB = (unsigned char*)ws;                         // 4 MiB packed fp8 f_
  unsigned char* pkA = (unsigned char*)(ws + 4u * 1024u * 1024u);  // 4 MiB packed fp8 f
  float* gnh = (float*)(ws + 8u * 1024u * 1024u);                  // 128 KiB (-gn2/2)
  float* fnh = gnh + TOTAL_ROWS;                                   // 128 KiB (-fn2/2)
  unsigned int* rowmin = (unsigned int*)(fnh + TOTAL_ROWS);        // 128 KiB
  unsigned int* colmin = rowmin + TOTAL_ROWS;                      // 128 KiB

  pack_kernel<<<4096, 256, 0, stream>>>(f, f_, pkA, pkB, fnh, gnh, rowmin, colmin);
  chamfer_mfma_kernel<<<1024, 256, 0, stream>>>(pkA, pkB, fnh, gnh, rowmin, colmin);
  reduce_kernel<<<1, 1024, 0, stream>>>(rowmin, colmin, (float*)d_out);
}

// Round 20
// 57.786 us; speedup vs baseline: 1.0458x; 1.0458x over previous
//
#include <hip/hip_runtime.h>

#define BATCH 4
#define NPTS 8192
#define DIM 128
#define TOTAL_ROWS (BATCH * NPTS)   // 32768
#define SLICES 8                    // m-slices per batch
#define SLICE_W 1024                // cols per slice
#define ITERS 64                    // 16-col tiles per slice
#define TILES_PER_B 512             // NPTS/16
#define TILE_B 2048                 // bytes per packed fp8 16-col tile

typedef __attribute__((ext_vector_type(8))) int   i32x8;
typedef __attribute__((ext_vector_type(4))) float f32x4;

// monotonic encoding of float for unsigned atomicMin (3 ops: ashr, or, xor)
__device__ __forceinline__ unsigned encf(float f) {
  unsigned b = __float_as_uint(f);
  return b ^ ((unsigned)((int)b >> 31) | 0x80000000u);
}
__device__ __forceinline__ float decf(unsigned u) {
  unsigned b = (u & 0x80000000u) ? (u ^ 0x80000000u) : ~u;
  return __uint_as_float(b);
}

// pack 8 floats -> 8 fp8(e4m3) bytes in 2 dwords
__device__ __forceinline__ void pk8(const float4& x, const float4& y,
                                    unsigned& lo, unsigned& hi) {
  lo = __builtin_amdgcn_cvt_pk_fp8_f32(x.x, x.y, 0, 0);
  lo = __builtin_amdgcn_cvt_pk_fp8_f32(x.z, x.w, lo, 1);
  hi = __builtin_amdgcn_cvt_pk_fp8_f32(y.x, y.y, 0, 0);
  hi = __builtin_amdgcn_cvt_pk_fp8_f32(y.z, y.w, hi, 1);
}

// ---- fused pack: blocks <2048 pack f_ (pkB,gnh); >=2048 pack f (pkA,fnh).
// Each block also inits 8 entries of rowmin + colmin (replaces 2 memsets).
__global__ void pack_kernel(const float* __restrict__ f,
                            const float* __restrict__ f_,
                            unsigned char* __restrict__ pkA,
                            unsigned char* __restrict__ pkB,
                            float* __restrict__ fnh,
                            float* __restrict__ gnh,
                            unsigned int* __restrict__ rowmin,
                            unsigned int* __restrict__ colmin) {
  __shared__ float sred[16][17];
  int gb  = blockIdx.x;                // 0..4095
  int tl  = threadIdx.x;               // 0..255
  if (tl < 8)        rowmin[gb * 8 + tl]       = 0xFFFFFFFFu;
  else if (tl < 16)  colmin[gb * 8 + (tl - 8)] = 0xFFFFFFFFu;

  const int isA = gb >> 11;            // 0: f_ -> pkB ; 1: f -> pkA
  const float* in = isA ? f : f_;
  unsigned char* pk = isA ? pkA : pkB;
  float* n2h = isA ? fnh : gnh;

  int fl  = tl >> 2;                   // fragment lane 0..63
  int p   = tl & 3;                    // 8-byte group within lane's 32
  int row = fl & 15, kch = fl >> 4;
  int tile = gb & 2047;                // b*512 + mtg
  int b = tile >> 9, mtg = tile & 511;
  const float* src = in + (size_t)(b * NPTS + mtg * 16 + row) * DIM + kch * 32 + p * 8;
  float4 x = ((const float4*)src)[0], y = ((const float4*)src)[1];
  unsigned lo, hi;
  pk8(x, y, lo, hi);
  *(uint2*)(pk + (size_t)tile * TILE_B + fl * 32 + p * 8) = make_uint2(lo, hi);
  float s = 0.f;
  s = fmaf(x.x, x.x, s); s = fmaf(x.y, x.y, s);
  s = fmaf(x.z, x.z, s); s = fmaf(x.w, x.w, s);
  s = fmaf(y.x, y.x, s); s = fmaf(y.y, y.y, s);
  s = fmaf(y.z, y.z, s); s = fmaf(y.w, y.w, s);
  sred[row][kch * 4 + p] = s;
  __syncthreads();
  if (tl < 16) {
    float t = 0.f;
    #pragma unroll
    for (int j = 0; j < 16; ++j) t += sred[tl][j];
    n2h[tile * 16 + tl] = -0.5f * t;   // store -n2/2
  }
}

// ---- main: per wave, 64 f-rows (packed fp8 A) x 1024-col slice ----
// fp8 K=128 MFMA, C-seeded with -fn2/2, dual-tile epilogue (max3 row side,
// e-form col side), no setprio, 4-buffer B prefetch. LB(256,3).
__global__ __launch_bounds__(256, 3)
void chamfer_mfma_kernel(const unsigned char* __restrict__ pkA,
                         const unsigned char* __restrict__ pkB,
                         const float* __restrict__ fnh,
                         const float* __restrict__ gnh,
                         unsigned int* __restrict__ rowmin,
                         unsigned int* __restrict__ colmin) {
  const int lane = threadIdx.x & 63;
  const int l15  = lane & 15;
  const int q    = lane >> 4;                       // 0..3
  const int widx = threadIdx.x >> 6;                // 0..3
  const int loff = lane * 32;                       // per-lane byte offset

  // XCD-aware: 4 (b,slice) combos per XCD, 32 row-groups each
  const int bid   = blockIdx.x;                     // 0..1023
  const int combo = (bid & 7) * 4 + ((bid >> 3) & 3);  // 0..31
  const int b     = combo >> 3;
  const int slice = combo & 7;
  const int rgrp  = bid >> 5;                       // 0..31
  const int r0    = rgrp * 256 + widx * 64;
  const int bN    = b * NPTS;
  const int tile0 = b * TILES_PER_B + slice * ITERS;

  // block-level column-max accumulator of encf(-2*cmax_e) (= min dis)
  __shared__ unsigned cl[SLICE_W];
  #pragma unroll
  for (int k = 0; k < SLICE_W / 256; ++k)
    cl[threadIdx.x + k * 256] = 0xFFFFFFFFu;
  __syncthreads();

  // ---- A fragments from packed pkA (uniform base + loff) ----
  i32x8 af[4];
  const int atile0 = b * TILES_PER_B + (r0 >> 4);
  #pragma unroll
  for (int t = 0; t < 4; ++t) {
    const unsigned char* ub = pkA + (size_t)(atile0 + t) * TILE_B;
    af[t] = *(const i32x8*)(ub + loff);
  }
  // C-seeds h = -fn2/2 (pre-halved in fnh) for this lane's C rows
  f32x4 h[4];
  #pragma unroll
  for (int t = 0; t < 4; ++t)
    #pragma unroll
    for (int i = 0; i < 4; ++i)
      h[t][i] = fnh[bN + r0 + t * 16 + q * 4 + i];

  float rowmax[4][4];
  #pragma unroll
  for (int t = 0; t < 4; ++t)
    #pragma unroll
    for (int i = 0; i < 4; ++i) rowmax[t][i] = -3.4e38f;

  const unsigned char* pkw = pkB + (size_t)tile0 * TILE_B;  // uniform
  const float*         gnb = gnh + bN + slice * SLICE_W;

  auto loadB = [&](int mt, i32x8& bf, float& gv) {
    const unsigned char* ub = pkw + (size_t)mt * TILE_B;    // uniform + SALU
    bf = *(const i32x8*)(ub + loff);
    gv = gnb[mt * 16 + l15];                                // = -gn2/2
  };

  auto mfma4 = [&](const i32x8& bf, f32x4 acc[4]) {
    #pragma unroll
    for (int t = 0; t < 4; ++t)
      acc[t] = __builtin_amdgcn_mfma_scale_f32_16x16x128_f8f6f4(
          af[t], bf, h[t], 0, 0, 0, 0x7f7f7f7f, 0, 0x7f7f7f7f);
  };

  // dual-tile epilogue: e = acc + g (= -dis/2); rowmax via max3; per-tile
  // col tree over e (8 ops, max3-fused); atomicMin stores min dis directly.
  auto epi2 = [&](const f32x4 a1[4], float ga, int mta,
                  const f32x4 a2[4], float gb, int mtb) {
    float e1[16], e2[16];
    #pragma unroll
    for (int t = 0; t < 4; ++t)
      #pragma unroll
      for (int i = 0; i < 4; ++i) {
        float x1 = a1[t][i] + ga;
        float x2 = a2[t][i] + gb;
        e1[t * 4 + i] = x1;
        e2[t * 4 + i] = x2;
        rowmax[t][i] = fmaxf(fmaxf(rowmax[t][i], x1), x2);  // v_max3
      }
    float m0 = fmaxf(fmaxf(e1[0], e1[1]), e1[2]);
    float m1 = fmaxf(fmaxf(e1[3], e1[4]), e1[5]);
    float m2 = fmaxf(fmaxf(e1[6], e1[7]), e1[8]);
    float m3 = fmaxf(fmaxf(e1[9], e1[10]), e1[11]);
    float m4 = fmaxf(fmaxf(e1[12], e1[13]), e1[14]);
    float n0 = fmaxf(fmaxf(m0, m1), m2);
    float n1 = fmaxf(fmaxf(m3, m4), e1[15]);
    float c1 = fmaxf(n0, n1);
    atomicMin(&cl[mta * 16 + l15], encf(-2.f * c1));
    float p0 = fmaxf(fmaxf(e2[0], e2[1]), e2[2]);
    float p1 = fmaxf(fmaxf(e2[3], e2[4]), e2[5]);
    float p2 = fmaxf(fmaxf(e2[6], e2[7]), e2[8]);
    float p3 = fmaxf(fmaxf(e2[9], e2[10]), e2[11]);
    float p4 = fmaxf(fmaxf(e2[12], e2[13]), e2[14]);
    float q0 = fmaxf(fmaxf(p0, p1), p2);
    float q1 = fmaxf(fmaxf(p3, p4), e2[15]);
    float c2 = fmaxf(q0, q1);
    atomicMin(&cl[mtb * 16 + l15], encf(-2.f * c2));
  };

  // 4-buffer B prefetch, tiles processed in pairs
  i32x8 b0, b1, b2, b3;
  float g0, g1, g2v, g3;
  loadB(0, b0, g0); loadB(1, b1, g1); loadB(2, b2, g2v); loadB(3, b3, g3);
  f32x4 acc1[4], acc2[4];
  #pragma unroll 2
  for (int mt = 0; mt < ITERS; mt += 4) {
    mfma4(b0, acc1); mfma4(b1, acc2);
    epi2(acc1, g0, mt, acc2, g1, mt + 1);
    loadB((mt + 4) & (ITERS - 1), b0, g0);
    loadB((mt + 5) & (ITERS - 1), b1, g1);
    mfma4(b2, acc1); mfma4(b3, acc2);
    epi2(acc1, g2v, mt + 2, acc2, g3, mt + 3);
    loadB((mt + 6) & (ITERS - 1), b2, g2v);
    loadB((mt + 7) & (ITERS - 1), b3, g3);
  }

  // finalize row mins: reduce MAX over the 16 column-lanes, dis = -2*max
  #pragma unroll
  for (int t = 0; t < 4; ++t)
    #pragma unroll
    for (int i = 0; i < 4; ++i) {
      float v = rowmax[t][i];
      v = fmaxf(v, __shfl_xor(v, 1));
      v = fmaxf(v, __shfl_xor(v, 2));
      v = fmaxf(v, __shfl_xor(v, 4));
      v = fmaxf(v, __shfl_xor(v, 8));
      if (l15 == 0)
        atomicMin(&rowmin[bN + r0 + t * 16 + q * 4 + i], encf(-2.f * v));
    }

  // merge block col mins (already full dis) into global
  __syncthreads();
  #pragma unroll
  for (int k = 0; k < SLICE_W / 256; ++k) {
    int c = threadIdx.x + k * 256;
    atomicMin(&colmin[bN + slice * SLICE_W + c], cl[c]);
  }
}

// ---- single-kernel reduction: 1 block x 1024 thr, grid-stride ----
__global__ void reduce_kernel(const unsigned int* __restrict__ rowmin,
                              const unsigned int* __restrict__ colmin,
                              float* __restrict__ out) {
  __shared__ float sbuf[16];
  float s = 0.f;
  for (int i = threadIdx.x; i < TOTAL_ROWS; i += 1024)
    s += decf(rowmin[i]) + decf(colmin[i]);
  #pragma unroll
  for (int o = 32; o >= 1; o >>= 1) s += __shfl_xor(s, o);
  if ((threadIdx.x & 63) == 0) sbuf[threadIdx.x >> 6] = s;
  __syncthreads();
  if (threadIdx.x == 0) {
    float t = 0.f;
    #pragma unroll
    for (int j = 0; j < 16; ++j) t += sbuf[j];
    out[0] = t / (float)TOTAL_ROWS;
  }
}

extern "C" void kernel_launch(void* const* d_in, const int* in_sizes, int n_in,
                              void* d_out, int out_size, void* d_ws, size_t ws_size,
                              hipStream_t stream) {
  (void)in_sizes; (void)n_in; (void)out_size; (void)ws_size;
  const float* f  = (const float*)d_in[0];
  const float* f_ = (const float*)d_in[1];

  char* ws = (char*)d_ws;
  unsigned char* pkB = (unsigned char*)ws;                         // 4 MiB packed fp8 f_
  unsigned char* pkA = (unsigned char*)(ws + 4u * 1024u * 1024u);  // 4 MiB packed fp8 f
  float* gnh = (float*)(ws + 8u * 1024u * 1024u);                  // 128 KiB (-gn2/2)
  float* fnh = gnh + TOTAL_ROWS;                                   // 128 KiB (-fn2/2)
  unsigned int* rowmin = (unsigned int*)(fnh + TOTAL_ROWS);        // 128 KiB
  unsigned int* colmin = rowmin + TOTAL_ROWS;                      // 128 KiB

  pack_kernel<<<4096, 256, 0, stream>>>(f, f_, pkA, pkB, fnh, gnh, rowmin, colmin);
  chamfer_mfma_kernel<<<1024, 256, 0, stream>>>(pkA, pkB, fnh, gnh, rowmin, colmin);
  reduce_kernel<<<1, 1024, 0, stream>>>(rowmin, colmin, (float*)d_out);
}

// Round 21
// 55.335 us; speedup vs baseline: 1.0921x; 1.0443x over previous
//
#include <hip/hip_runtime.h>

#define BATCH 4
#define NPTS 8192
#define DIM 128
#define TOTAL_ROWS (BATCH * NPTS)   // 32768
#define SLICES 8                    // m-slices per batch
#define SLICE_W 1024                // cols per slice
#define ITERS 64                    // 16-col tiles per slice
#define TILES_PER_B 512             // NPTS/16
#define TILE_B 2048                 // bytes per packed fp8 16-col tile

typedef __attribute__((ext_vector_type(8))) int   i32x8;
typedef __attribute__((ext_vector_type(4))) float f32x4;

// monotonic encoding of float for unsigned atomicMin (3 ops: ashr, or, xor)
__device__ __forceinline__ unsigned encf(float f) {
  unsigned b = __float_as_uint(f);
  return b ^ ((unsigned)((int)b >> 31) | 0x80000000u);
}
__device__ __forceinline__ float decf(unsigned u) {
  unsigned b = (u & 0x80000000u) ? (u ^ 0x80000000u) : ~u;
  return __uint_as_float(b);
}

// pack 8 floats -> 8 fp8(e4m3) bytes in 2 dwords
__device__ __forceinline__ void pk8(const float4& x, const float4& y,
                                    unsigned& lo, unsigned& hi) {
  lo = __builtin_amdgcn_cvt_pk_fp8_f32(x.x, x.y, 0, 0);
  lo = __builtin_amdgcn_cvt_pk_fp8_f32(x.z, x.w, lo, 1);
  hi = __builtin_amdgcn_cvt_pk_fp8_f32(y.x, y.y, 0, 0);
  hi = __builtin_amdgcn_cvt_pk_fp8_f32(y.z, y.w, hi, 1);
}

// ---- fused pack: blocks <2048 pack f_ (pkB,gnh); >=2048 pack f (pkA,fnh).
// Each block also inits 8 entries of rowmin + colmin; block 0 zeroes counter.
__global__ void pack_kernel(const float* __restrict__ f,
                            const float* __restrict__ f_,
                            unsigned char* __restrict__ pkA,
                            unsigned char* __restrict__ pkB,
                            float* __restrict__ fnh,
                            float* __restrict__ gnh,
                            unsigned int* __restrict__ rowmin,
                            unsigned int* __restrict__ colmin,
                            unsigned int* __restrict__ counter) {
  __shared__ float sred[16][17];
  int gb  = blockIdx.x;                // 0..4095
  int tl  = threadIdx.x;               // 0..255
  if (tl < 8)        rowmin[gb * 8 + tl]       = 0xFFFFFFFFu;
  else if (tl < 16)  colmin[gb * 8 + (tl - 8)] = 0xFFFFFFFFu;
  if (gb == 0 && tl == 16) counter[0] = 0u;   // graph-replay-safe reset

  const int isA = gb >> 11;            // 0: f_ -> pkB ; 1: f -> pkA
  const float* in = isA ? f : f_;
  unsigned char* pk = isA ? pkA : pkB;
  float* n2h = isA ? fnh : gnh;

  int fl  = tl >> 2;                   // fragment lane 0..63
  int p   = tl & 3;                    // 8-byte group within lane's 32
  int row = fl & 15, kch = fl >> 4;
  int tile = gb & 2047;                // b*512 + mtg
  int b = tile >> 9, mtg = tile & 511;
  const float* src = in + (size_t)(b * NPTS + mtg * 16 + row) * DIM + kch * 32 + p * 8;
  float4 x = ((const float4*)src)[0], y = ((const float4*)src)[1];
  unsigned lo, hi;
  pk8(x, y, lo, hi);
  *(uint2*)(pk + (size_t)tile * TILE_B + fl * 32 + p * 8) = make_uint2(lo, hi);
  float s = 0.f;
  s = fmaf(x.x, x.x, s); s = fmaf(x.y, x.y, s);
  s = fmaf(x.z, x.z, s); s = fmaf(x.w, x.w, s);
  s = fmaf(y.x, y.x, s); s = fmaf(y.y, y.y, s);
  s = fmaf(y.z, y.z, s); s = fmaf(y.w, y.w, s);
  sred[row][kch * 4 + p] = s;
  __syncthreads();
  if (tl < 16) {
    float t = 0.f;
    #pragma unroll
    for (int j = 0; j < 16; ++j) t += sred[tl][j];
    n2h[tile * 16 + tl] = -0.5f * t;   // store -n2/2
  }
}

// ---- main: per wave, 64 f-rows (packed fp8 A) x 1024-col slice ----
// (byte-identical to R20's main kernel)
__global__ __launch_bounds__(256, 3)
void chamfer_mfma_kernel(const unsigned char* __restrict__ pkA,
                         const unsigned char* __restrict__ pkB,
                         const float* __restrict__ fnh,
                         const float* __restrict__ gnh,
                         unsigned int* __restrict__ rowmin,
                         unsigned int* __restrict__ colmin) {
  const int lane = threadIdx.x & 63;
  const int l15  = lane & 15;
  const int q    = lane >> 4;                       // 0..3
  const int widx = threadIdx.x >> 6;                // 0..3
  const int loff = lane * 32;                       // per-lane byte offset

  // XCD-aware: 4 (b,slice) combos per XCD, 32 row-groups each
  const int bid   = blockIdx.x;                     // 0..1023
  const int combo = (bid & 7) * 4 + ((bid >> 3) & 3);  // 0..31
  const int b     = combo >> 3;
  const int slice = combo & 7;
  const int rgrp  = bid >> 5;                       // 0..31
  const int r0    = rgrp * 256 + widx * 64;
  const int bN    = b * NPTS;
  const int tile0 = b * TILES_PER_B + slice * ITERS;

  // block-level column-max accumulator of encf(min dis)
  __shared__ unsigned cl[SLICE_W];
  #pragma unroll
  for (int k = 0; k < SLICE_W / 256; ++k)
    cl[threadIdx.x + k * 256] = 0xFFFFFFFFu;
  __syncthreads();

  // ---- A fragments from packed pkA (uniform base + loff) ----
  i32x8 af[4];
  const int atile0 = b * TILES_PER_B + (r0 >> 4);
  #pragma unroll
  for (int t = 0; t < 4; ++t) {
    const unsigned char* ub = pkA + (size_t)(atile0 + t) * TILE_B;
    af[t] = *(const i32x8*)(ub + loff);
  }
  // C-seeds h = -fn2/2 (pre-halved in fnh) for this lane's C rows
  f32x4 h[4];
  #pragma unroll
  for (int t = 0; t < 4; ++t)
    #pragma unroll
    for (int i = 0; i < 4; ++i)
      h[t][i] = fnh[bN + r0 + t * 16 + q * 4 + i];

  float rowmax[4][4];
  #pragma unroll
  for (int t = 0; t < 4; ++t)
    #pragma unroll
    for (int i = 0; i < 4; ++i) rowmax[t][i] = -3.4e38f;

  const unsigned char* pkw = pkB + (size_t)tile0 * TILE_B;  // uniform
  const float*         gnb = gnh + bN + slice * SLICE_W;

  auto loadB = [&](int mt, i32x8& bf, float& gv) {
    const unsigned char* ub = pkw + (size_t)mt * TILE_B;    // uniform + SALU
    bf = *(const i32x8*)(ub + loff);
    gv = gnb[mt * 16 + l15];                                // = -gn2/2
  };

  auto mfma4 = [&](const i32x8& bf, f32x4 acc[4]) {
    #pragma unroll
    for (int t = 0; t < 4; ++t)
      acc[t] = __builtin_amdgcn_mfma_scale_f32_16x16x128_f8f6f4(
          af[t], bf, h[t], 0, 0, 0, 0x7f7f7f7f, 0, 0x7f7f7f7f);
  };

  // dual-tile epilogue: e = acc + g (= -dis/2); rowmax via max3; per-tile
  // col tree over e (max3-fused); atomicMin stores min dis directly.
  auto epi2 = [&](const f32x4 a1[4], float ga, int mta,
                  const f32x4 a2[4], float gb, int mtb) {
    float e1[16], e2[16];
    #pragma unroll
    for (int t = 0; t < 4; ++t)
      #pragma unroll
      for (int i = 0; i < 4; ++i) {
        float x1 = a1[t][i] + ga;
        float x2 = a2[t][i] + gb;
        e1[t * 4 + i] = x1;
        e2[t * 4 + i] = x2;
        rowmax[t][i] = fmaxf(fmaxf(rowmax[t][i], x1), x2);  // v_max3
      }
    float m0 = fmaxf(fmaxf(e1[0], e1[1]), e1[2]);
    float m1 = fmaxf(fmaxf(e1[3], e1[4]), e1[5]);
    float m2 = fmaxf(fmaxf(e1[6], e1[7]), e1[8]);
    float m3 = fmaxf(fmaxf(e1[9], e1[10]), e1[11]);
    float m4 = fmaxf(fmaxf(e1[12], e1[13]), e1[14]);
    float n0 = fmaxf(fmaxf(m0, m1), m2);
    float n1 = fmaxf(fmaxf(m3, m4), e1[15]);
    float c1 = fmaxf(n0, n1);
    atomicMin(&cl[mta * 16 + l15], encf(-2.f * c1));
    float p0 = fmaxf(fmaxf(e2[0], e2[1]), e2[2]);
    float p1 = fmaxf(fmaxf(e2[3], e2[4]), e2[5]);
    float p2 = fmaxf(fmaxf(e2[6], e2[7]), e2[8]);
    float p3 = fmaxf(fmaxf(e2[9], e2[10]), e2[11]);
    float p4 = fmaxf(fmaxf(e2[12], e2[13]), e2[14]);
    float q0 = fmaxf(fmaxf(p0, p1), p2);
    float q1 = fmaxf(fmaxf(p3, p4), e2[15]);
    float c2 = fmaxf(q0, q1);
    atomicMin(&cl[mtb * 16 + l15], encf(-2.f * c2));
  };

  // 4-buffer B prefetch, tiles processed in pairs
  i32x8 b0, b1, b2, b3;
  float g0, g1, g2v, g3;
  loadB(0, b0, g0); loadB(1, b1, g1); loadB(2, b2, g2v); loadB(3, b3, g3);
  f32x4 acc1[4], acc2[4];
  #pragma unroll 2
  for (int mt = 0; mt < ITERS; mt += 4) {
    mfma4(b0, acc1); mfma4(b1, acc2);
    epi2(acc1, g0, mt, acc2, g1, mt + 1);
    loadB((mt + 4) & (ITERS - 1), b0, g0);
    loadB((mt + 5) & (ITERS - 1), b1, g1);
    mfma4(b2, acc1); mfma4(b3, acc2);
    epi2(acc1, g2v, mt + 2, acc2, g3, mt + 3);
    loadB((mt + 6) & (ITERS - 1), b2, g2v);
    loadB((mt + 7) & (ITERS - 1), b3, g3);
  }

  // finalize row mins: reduce MAX over the 16 column-lanes, dis = -2*max
  #pragma unroll
  for (int t = 0; t < 4; ++t)
    #pragma unroll
    for (int i = 0; i < 4; ++i) {
      float v = rowmax[t][i];
      v = fmaxf(v, __shfl_xor(v, 1));
      v = fmaxf(v, __shfl_xor(v, 2));
      v = fmaxf(v, __shfl_xor(v, 4));
      v = fmaxf(v, __shfl_xor(v, 8));
      if (l15 == 0)
        atomicMin(&rowmin[bN + r0 + t * 16 + q * 4 + i], encf(-2.f * v));
    }

  // merge block col mins (already full dis) into global
  __syncthreads();
  #pragma unroll
  for (int k = 0; k < SLICE_W / 256; ++k) {
    int c = threadIdx.x + k * 256;
    atomicMin(&colmin[bN + slice * SLICE_W + c], cl[c]);
  }
}

// ---- parallel reduce, single dispatch: 32 blocks x 256 thr, uint4 loads;
// last block (device-atomic counter) sums the 32 partials in fixed order.
__global__ void reduce_kernel(const unsigned int* __restrict__ mins, // 65536
                              float* __restrict__ partial,           // [32]
                              unsigned int* __restrict__ counter,
                              float* __restrict__ out) {
  __shared__ float sbuf[4];
  int base = blockIdx.x * 2048 + threadIdx.x * 8;
  uint4 a = *(const uint4*)(mins + base);
  uint4 c = *(const uint4*)(mins + base + 4);
  float s = decf(a.x) + decf(a.y) + decf(a.z) + decf(a.w)
          + decf(c.x) + decf(c.y) + decf(c.z) + decf(c.w);
  #pragma unroll
  for (int o = 32; o >= 1; o >>= 1) s += __shfl_xor(s, o);
  if ((threadIdx.x & 63) == 0) sbuf[threadIdx.x >> 6] = s;
  __syncthreads();
  if (threadIdx.x == 0) {
    float p = sbuf[0] + sbuf[1] + sbuf[2] + sbuf[3];
    __hip_atomic_store(&partial[blockIdx.x], p, __ATOMIC_RELEASE,
                       __HIP_MEMORY_SCOPE_AGENT);
    unsigned old = __hip_atomic_fetch_add(counter, 1u, __ATOMIC_ACQ_REL,
                                          __HIP_MEMORY_SCOPE_AGENT);
    if (old == 31u) {                    // last block finishes
      float t = 0.f;
      #pragma unroll
      for (int j = 0; j < 32; ++j)
        t += __hip_atomic_load(&partial[j], __ATOMIC_ACQUIRE,
                               __HIP_MEMORY_SCOPE_AGENT);
      out[0] = t / (float)TOTAL_ROWS;
    }
  }
}

extern "C" void kernel_launch(void* const* d_in, const int* in_sizes, int n_in,
                              void* d_out, int out_size, void* d_ws, size_t ws_size,
                              hipStream_t stream) {
  (void)in_sizes; (void)n_in; (void)out_size; (void)ws_size;
  const float* f  = (const float*)d_in[0];
  const float* f_ = (const float*)d_in[1];

  char* ws = (char*)d_ws;
  unsigned char* pkB = (unsigned char*)ws;                         // 4 MiB packed fp8 f_
  unsigned char* pkA = (unsigned char*)(ws + 4u * 1024u * 1024u);  // 4 MiB packed fp8 f
  float* gnh = (float*)(ws + 8u * 1024u * 1024u);                  // 128 KiB (-gn2/2)
  float* fnh = gnh + TOTAL_ROWS;                                   // 128 KiB (-fn2/2)
  unsigned int* rowmin = (unsigned int*)(fnh + TOTAL_ROWS);        // 128 KiB
  unsigned int* colmin = rowmin + TOTAL_ROWS;                      // 128 KiB (contiguous!)
  float* partial = (float*)(colmin + TOTAL_ROWS);                  // 128 B
  unsigned int* counter = (unsigned int*)(partial + 32);           // 4 B

  pack_kernel<<<4096, 256, 0, stream>>>(f, f_, pkA, pkB, fnh, gnh,
                                        rowmin, colmin, counter);
  chamfer_mfma_kernel<<<1024, 256, 0, stream>>>(pkA, pkB, fnh, gnh, rowmin, colmin);
  reduce_kernel<<<32, 256, 0, stream>>>(rowmin, partial, counter, (float*)d_out);
}